// Round 6
// baseline (194.718 us; speedup 1.0000x reference)
//
#include <hip/hip_runtime.h>
#include <hip/hip_bf16.h>

// Problem constants
#define B_SZ 8
#define L_SZ 2048
#define DM   512
#define HIDC 1024            // complex hidden channels
#define NROW (B_SZ*L_SZ)     // 16384
#define NCOL (2*HIDC)        // 2048 (re || im)
#define LCH  128             // scan chunk length
#define NCH  (L_SZ/LCH)      // 16 chunks

typedef __attribute__((ext_vector_type(8))) short bf16x8;
typedef __attribute__((ext_vector_type(4))) float f32x4;

typedef __attribute__((address_space(1))) const void gvoid_t;
typedef __attribute__((address_space(3))) void lvoid_t;

__device__ __forceinline__ void gload_lds16(const void* g, void* l) {
  __builtin_amdgcn_global_load_lds((gvoid_t*)g, (lvoid_t*)l, 16, 0, 0);
}

__device__ __forceinline__ unsigned short f2bf(float v) {
  return __builtin_bit_cast(unsigned short, __float2bfloat16(v));
}
__device__ __forceinline__ float bf2f(unsigned short u) {
  return __bfloat162float(__builtin_bit_cast(__hip_bfloat16, u));
}

// ---------------- prep kernels ----------------
__global__ void k_cvt_x(const float* __restrict__ x, unsigned short* __restrict__ xb) {
  long i = (long)blockIdx.x * 256 + threadIdx.x;
  float4 v = ((const float4*)x)[i];
  ushort4 o;
  o.x = f2bf(v.x); o.y = f2bf(v.y); o.z = f2bf(v.z); o.w = f2bf(v.w);
  ((ushort4*)xb)[i] = o;
}

__global__ void k_prep_w1(const float* __restrict__ Wr, const float* __restrict__ Wi,
                          const float* __restrict__ br, const float* __restrict__ bi,
                          const float* __restrict__ gamma_log,
                          unsigned short* __restrict__ W1b, float* __restrict__ b1) {
  long idx = (long)blockIdx.x * 256 + threadIdx.x; // 2048*512
  int n = (int)(idx >> 9), k = (int)(idx & 511);
  int d = n & (HIDC - 1);
  float g = __expf(gamma_log[d]);
  float w = (n < HIDC) ? Wr[(long)d * DM + k] : Wi[(long)d * DM + k];
  W1b[idx] = f2bf(g * w);
  if (k == 0) b1[n] = g * ((n < HIDC) ? br[d] : bi[d]);
}

__global__ void k_prep_w2(const float* __restrict__ Wor, const float* __restrict__ Woi,
                          unsigned short* __restrict__ W2b) {
  long idx = (long)blockIdx.x * 256 + threadIdx.x; // 512*2048
  int e = (int)(idx >> 11), k = (int)(idx & 2047);
  float w = (k < HIDC) ? Wor[(long)e * HIDC + k] : -Woi[(long)e * HIDC + (k - HIDC)];
  W2b[idx] = f2bf(w);
}

__global__ void k_prep_lam(const float* __restrict__ nu_log, const float* __restrict__ theta_log,
                           float* __restrict__ lam) {
  int d = blockIdx.x * 256 + threadIdx.x;
  if (d >= HIDC) return;
  float nu = __expf(nu_log[d]);
  float th = __expf(theta_log[d]);
  float mag = __expf(-nu);
  lam[d]        = mag * cosf(th);
  lam[HIDC + d] = mag * sinf(th);
}

// ================= GEMM1: 8-phase 256x256 (T3+T4+T2+T5) =================
// C[16384][2048](bf16) = A[16384][512] * Bw[2048][512]^T + bias.
// BM=BN=256, BK=64; 512 thr = 8 waves (2M x 4N), per-wave 128x64 (8x4 frags).
// LDS 128KB: As[2][256][64], Bs[2][256][64] bf16; K-tile t lives in buf t&1.
// Per iteration i: phases 0-3 compute K-tile 2i (buf0), 4-7 K-tile 2i+1 (buf1).
// Stage granule = one gload_lds round = 64 rows (8KB). Per-phase stages:
//   ph0: buf1 A g1,g3 [K-tile 2i+1]   (regions last read ph6,7 of iter i-1)
//   ph1: buf0 B g0,g1 [2i+2]          (B buf0 last read ph0: fb)
//   ph2: buf0 B g2,g3
//   ph3: buf0 A g0,g2                 (rows 0-63/128-191 last read ph0,1)
//   ph4: buf0 A g1,g3                 (rows 64-127/192-255 last read ph2,3)
//   ph5: buf1 B g0,g1 [2i+3]          (B buf1 last read ph4)
//   ph6: buf1 B g2,g3
//   ph7: buf1 A g0,g2                 (rows last read ph4,5)
// Every stage issues AFTER the barrier that follows its region's last read
// => no WAR race. RAW: vmcnt retires in-order (m135); vmcnt(6) at end-ph3
// leaves only ph1-3's 6 loads outstanding => buf1 (ph5-7 of i-1 + ph0) landed
// before ph4 reads; vmcnt(6) at end-ph7 leaves ph5-7 outstanding => buf0
// (ph1-4) landed before next iter's ph0 reads.
// Swizzle (both-sides): 128B rows, slot' = slot ^ (row&7); store side via
// pre-swizzled GLOBAL source (LDS dest linear, rule 21), read side on the
// ds_read offset; row&7 = fr&7 for all fragment rows.
__global__ __launch_bounds__(512, 2)
void gemm1_8ph(const unsigned short* __restrict__ A, const unsigned short* __restrict__ Bw,
               unsigned short* __restrict__ C, const float* __restrict__ bias) {
  constexpr int K  = DM;        // 512
  constexpr int NI = K / 128;   // 4 iterations (2 K-tiles each)
  extern __shared__ unsigned short lds[];   // As: [0,32768) ; Bs: [32768,65536)

  const int tid = threadIdx.x;
  const int w = tid >> 6, lane = tid & 63;
  const int wr = w >> 2, wc = w & 3;        // 2M x 4N wave grid
  const int fr = lane & 15, lq = lane >> 4;

  // XCD 2-D blocking: 512 blocks = 64 m-tiles x 8 n-tiles; XCD owns 8 m x all n
  const int xcd = blockIdx.x & 7;
  const int idx = blockIdx.x >> 3;
  const int mt  = xcd * 8 + (idx >> 3);
  const int nt  = idx & 7;
  const long m0 = (long)mt * 256, n0 = (long)nt * 256;

  // staging: 512 thr x 16B = 8KB = 64 rows(128B) per gload
  const int srow  = tid >> 3;
  const int gslot = (tid & 7) ^ ((tid >> 3) & 7);   // pre-swizzled source slot
  const unsigned short* Agp = A  + (m0 + srow) * (long)K + gslot * 8;
  const unsigned short* Bgp = Bw + (n0 + srow) * (long)K + gslot * 8;
  const int ldst = tid * 8;

#define SA1(d, t, g) gload_lds16(Agp + (t) * 64 + (long)((g) * 64) * K,          \
                                 &lds[(d) * 16384 + (g) * 4096 + ldst])
#define SB1(d, t, g) gload_lds16(Bgp + (t) * 64 + (long)((g) * 64) * K,          \
                                 &lds[32768 + (d) * 16384 + (g) * 4096 + ldst])

  // ds_read swizzled slot offsets (ushorts): ((ks*4+lq)^(fr&7))*8
  const int sx0 = ((0 + lq) ^ (fr & 7)) << 3;
  const int sx1 = ((4 + lq) ^ (fr & 7)) << 3;

  bf16x8 fb[4][2], fa[2][2];
  f32x4 acc[8][4] = {};

#define LDFB(d) { _Pragma("unroll")                                              \
    for (int n = 0; n < 4; n++) {                                                \
      fb[n][0] = *(const bf16x8*)&lds[32768 + (d)*16384 + (wc*64 + n*16 + fr)*64 + sx0]; \
      fb[n][1] = *(const bf16x8*)&lds[32768 + (d)*16384 + (wc*64 + n*16 + fr)*64 + sx1]; } }
#define LDFA(d, p) {                                                             \
      fa[0][0] = *(const bf16x8*)&lds[(d)*16384 + (wr*128 + (2*(p)  )*16 + fr)*64 + sx0]; \
      fa[0][1] = *(const bf16x8*)&lds[(d)*16384 + (wr*128 + (2*(p)  )*16 + fr)*64 + sx1]; \
      fa[1][0] = *(const bf16x8*)&lds[(d)*16384 + (wr*128 + (2*(p)+1)*16 + fr)*64 + sx0]; \
      fa[1][1] = *(const bf16x8*)&lds[(d)*16384 + (wr*128 + (2*(p)+1)*16 + fr)*64 + sx1]; }
#define MM16(p) { __builtin_amdgcn_s_setprio(1);                                 \
    _Pragma("unroll") for (int j = 0; j < 2; j++)                                \
    _Pragma("unroll") for (int n = 0; n < 4; n++) {                              \
      acc[2*(p)+j][n] = __builtin_amdgcn_mfma_f32_16x16x32_bf16(fa[j][0], fb[n][0], acc[2*(p)+j][n], 0, 0, 0); \
      acc[2*(p)+j][n] = __builtin_amdgcn_mfma_f32_16x16x32_bf16(fa[j][1], fb[n][1], acc[2*(p)+j][n], 0, 0, 0); } \
    __builtin_amdgcn_s_setprio(0); }
#define BARR { __builtin_amdgcn_s_barrier(); __builtin_amdgcn_sched_barrier(0); }
#define VM6  asm volatile("s_waitcnt vmcnt(6)" ::: "memory");
#define VM0  asm volatile("s_waitcnt vmcnt(0)" ::: "memory");

  // prologue: buf0 <- K-tile 0 (8 gloads), buf1 <- K-tile 1 minus A g1,g3 (6)
  SA1(0,0,0); SA1(0,0,1); SA1(0,0,2); SA1(0,0,3);
  SB1(0,0,0); SB1(0,0,1); SB1(0,0,2); SB1(0,0,3);
  SB1(1,1,0); SB1(1,1,1); SB1(1,1,2); SB1(1,1,3);
  SA1(1,1,0); SA1(1,1,2);
  VM6;                                  // buf0 fully landed (6 = buf1's loads)
  BARR;

  for (int i = 0; i < NI - 1; ++i) {
    const int t1 = 2*i+1, t2 = 2*i+2, t3 = 2*i+3;
    // ph0
    LDFB(0); LDFA(0,0); SA1(1,t1,1); SA1(1,t1,3); BARR; MM16(0); BARR;
    // ph1
    LDFA(0,1); SB1(0,t2,0); SB1(0,t2,1); BARR; MM16(1); BARR;
    // ph2
    LDFA(0,2); SB1(0,t2,2); SB1(0,t2,3); BARR; MM16(2); BARR;
    // ph3
    LDFA(0,3); SA1(0,t2,0); SA1(0,t2,2); BARR; MM16(3); VM6; BARR;
    // ph4
    LDFB(1); LDFA(1,0); SA1(0,t2,1); SA1(0,t2,3); BARR; MM16(0); BARR;
    // ph5
    LDFA(1,1); SB1(1,t3,0); SB1(1,t3,1); BARR; MM16(1); BARR;
    // ph6
    LDFA(1,2); SB1(1,t3,2); SB1(1,t3,3); BARR; MM16(2); BARR;
    // ph7
    LDFA(1,3); SA1(1,t3,0); SA1(1,t3,2); BARR; MM16(3); VM6; BARR;
  }
  // final iteration: only ph0's stage (buf1 A g1,g3 of last K-tile)
  {
    const int t1 = 2*NI - 1;
    LDFB(0); LDFA(0,0); SA1(1,t1,1); SA1(1,t1,3); BARR; MM16(0); BARR;
    LDFA(0,1); BARR; MM16(1); BARR;
    LDFA(0,2); BARR; MM16(2); BARR;
    LDFA(0,3); BARR; MM16(3); VM0; BARR;
    LDFB(1); LDFA(1,0); BARR; MM16(0); BARR;
    LDFA(1,1); BARR; MM16(1); BARR;
    LDFA(1,2); BARR; MM16(2); BARR;
    LDFA(1,3); BARR; MM16(3);
  }
#undef SA1
#undef SB1
#undef LDFB
#undef LDFA
#undef MM16
#undef BARR
#undef VM6
#undef VM0

  // epilogue: C/D layout col=lane&15, row=(lane>>4)*4+r (m89-verified)
  const int cr0 = lq * 4, cc = fr;
#pragma unroll
  for (int m = 0; m < 8; m++) {
#pragma unroll
    for (int n = 0; n < 4; n++) {
      long col = n0 + wc * 64 + n * 16 + cc;
      float bv = bias[col];
#pragma unroll
      for (int r = 0; r < 4; r++) {
        long row = m0 + wr * 128 + m * 16 + cr0 + r;
        C[row * (long)NCOL + col] = f2bf(acc[m][n][r] + bv);
      }
    }
  }
}

// ---------------- pipelined bf16 MFMA GEMM (v5) — GEMM2 only ----------------
// (proven R5 structure: BM=MF*32, BN=128, BK=32, 4 waves, triple-buffer,
//  counted vmcnt, both-sides swizzle slot^((row>>1)&3); 0 bank conflicts)
template<int MF, int OUT_BF16, int HAS_RESID, int LGY>
__global__ __launch_bounds__(256, 2)
void gemm_pipe(const unsigned short* __restrict__ A, const unsigned short* __restrict__ Bw,
               void* __restrict__ C, const float* __restrict__ bias,
               const unsigned short* __restrict__ resid, int M, int N, int K) {
  constexpr int BM     = MF * 32;
  constexpr int AUNITS = MF / 2;
  constexpr int LT     = AUNITS + 2;
  constexpr int ABUF   = BM * 32;
  constexpr int BBUF   = 128 * 32;

  extern __shared__ unsigned short lds[];
  unsigned short* As = lds;
  unsigned short* Bs = lds + 3 * ABUF;

  const int tid  = threadIdx.x;
  const int w    = tid >> 6, lane = tid & 63;
  const int wr   = w >> 1,   wc   = w & 1;
  const int fr   = lane & 15, lq  = lane >> 4;

  const int gx   = M / BM;
  const int xcd  = blockIdx.x & 7;
  const int idx  = blockIdx.x >> 3;
  const int mt   = xcd * (gx >> 3) + (idx >> LGY);
  const int nt   = idx & ((1 << LGY) - 1);
  const long m0  = (long)mt * BM;
  const long n0  = (long)nt * 128;

  const int srow  = tid >> 2;
  const int gslot = (tid & 3) ^ ((tid >> 3) & 3);
  const unsigned short* Agp = A  + (m0 + srow) * (long)K + gslot * 8;
  const unsigned short* Bgp = Bw + (n0 + srow) * (long)K + gslot * 8;
  const int ldst = tid * 8;

#define STAGE(t, b) {                                                        \
    long ko = (long)(t) * 32;                                                \
    _Pragma("unroll")                                                        \
    for (int u = 0; u < AUNITS; u++)                                         \
      gload_lds16(Agp + ko + (long)(u * 64) * K,                             \
                  &As[(b) * ABUF + u * 2048 + ldst]);                        \
    gload_lds16(Bgp + ko,                  &Bs[(b) * BBUF +        ldst]);   \
    gload_lds16(Bgp + ko + (long)64 * K,   &Bs[(b) * BBUF + 2048 + ldst]); }

  const int sx = (lq ^ ((fr >> 1) & 3)) << 3;

  f32x4 acc[MF][4] = {};
  const int NT = K >> 5;

  STAGE(0, 0);
  STAGE(1, 1);
  if constexpr (LT == 6) asm volatile("s_waitcnt vmcnt(6)" ::: "memory");
  else                   asm volatile("s_waitcnt vmcnt(4)" ::: "memory");
  __builtin_amdgcn_s_barrier();
  __builtin_amdgcn_sched_barrier(0);

  int cb = 0, bt2 = 2;
  for (int t = 0; t < NT; ++t) {
    if (t + 2 < NT) STAGE(t + 2, bt2);

    const unsigned short* Ab = As + cb * ABUF;
    const unsigned short* Bb = Bs + cb * BBUF;
    bf16x8 fa[MF], fb[4];
#pragma unroll
    for (int m = 0; m < MF; m++)
      fa[m] = *(const bf16x8*)&Ab[(wr * (MF * 16) + m * 16 + fr) * 32 + sx];
#pragma unroll
    for (int n = 0; n < 4; n++)
      fb[n] = *(const bf16x8*)&Bb[(wc * 64 + n * 16 + fr) * 32 + sx];
    __builtin_amdgcn_s_setprio(1);
#pragma unroll
    for (int m = 0; m < MF; m++)
#pragma unroll
      for (int n = 0; n < 4; n++)
        acc[m][n] = __builtin_amdgcn_mfma_f32_16x16x32_bf16(fa[m], fb[n], acc[m][n], 0, 0, 0);
    __builtin_amdgcn_s_setprio(0);

    if (t < NT - 1) {
      if (t + 2 < NT) {
        if constexpr (LT == 6) asm volatile("s_waitcnt vmcnt(6)" ::: "memory");
        else                   asm volatile("s_waitcnt vmcnt(4)" ::: "memory");
      } else {
        asm volatile("s_waitcnt vmcnt(0)" ::: "memory");
      }
      __builtin_amdgcn_s_barrier();
      __builtin_amdgcn_sched_barrier(0);
    }
    cb  = (cb  == 2) ? 0 : cb + 1;
    bt2 = (bt2 == 2) ? 0 : bt2 + 1;
  }
#undef STAGE

  const int cr0 = lq * 4, cc = fr;
#pragma unroll
  for (int m = 0; m < MF; m++) {
#pragma unroll
    for (int n = 0; n < 4; n++) {
      long col = n0 + wc * 64 + n * 16 + cc;
      float bv = bias[col];
#pragma unroll
      for (int r = 0; r < 4; r++) {
        long row = m0 + wr * (MF * 16) + m * 16 + cr0 + r;
        float v = acc[m][n][r] + bv;
        if (HAS_RESID) v += bf2f(resid[row * (long)N + col]);
        if (OUT_BF16)
          ((unsigned short*)C)[row * (long)N + col] = f2bf(v);
        else
          ((float*)C)[row * (long)N + col] = v;
      }
    }
  }
}

// ---------------- chunked scan (3 passes), in-place on ubuf (bf16) ----------------
__global__ void k_scan_local(const __hip_bfloat16* __restrict__ u,
                             const float* __restrict__ lam,
                             const float* __restrict__ mask,
                             float* __restrict__ E) {
  int b = blockIdx.x, c = blockIdx.y, dg = blockIdx.z, t = threadIdx.x;
  int d = dg * 256 + t;
  float lr = lam[d], li = lam[HIDC + d];
  float hr = 0.f, hi = 0.f;
  const __hip_bfloat16* ur = u + ((long)(b * L_SZ + c * LCH)) * NCOL + d;
  const __hip_bfloat16* ui = ur + HIDC;
  const float* mrow = mask + b * L_SZ + c * LCH;
  for (int l = 0; l < LCH; l++) {
    float xr = __bfloat162float(ur[(long)l * NCOL]);
    float xi = __bfloat162float(ui[(long)l * NCOL]);
    float g = (l > 0) ? mrow[l - 1] : 0.f;
    float nr = xr + g * (lr * hr - li * hi);
    float ni = xi + g * (lr * hi + li * hr);
    hr = nr; hi = ni;
  }
  E[(((long)b * NCH + c) * 2) * HIDC + d]     = hr;
  E[(((long)b * NCH + c) * 2 + 1) * HIDC + d] = hi;
}

__global__ void k_scan_carry(const float* __restrict__ E, const float* __restrict__ lam,
                             float* __restrict__ P) {
  int idx = blockIdx.x * 256 + threadIdx.x;   // 8192 = B * HIDC
  int b = idx >> 10, d = idx & (HIDC - 1);
  float lr = lam[d], li = lam[HIDC + d];
  float ar = lr, ai = li;                     // lam^128 via 7 squarings
  for (int s = 0; s < 7; s++) { float nr = ar * ar - ai * ai; float ni = 2.f * ar * ai; ar = nr; ai = ni; }
  float pr = 0.f, pi = 0.f;
  for (int c = 0; c < NCH; c++) {
    P[(((long)b * NCH + c) * 2) * HIDC + d]     = pr;
    P[(((long)b * NCH + c) * 2 + 1) * HIDC + d] = pi;
    float er = E[(((long)b * NCH + c) * 2) * HIDC + d];
    float ei = E[(((long)b * NCH + c) * 2 + 1) * HIDC + d];
    float nr = er + ar * pr - ai * pi;
    float ni = ei + ar * pi + ai * pr;
    pr = nr; pi = ni;
  }
}

__global__ void k_scan_final(__hip_bfloat16* __restrict__ u,
                             const float* __restrict__ lam,
                             const float* __restrict__ mask,
                             const float* __restrict__ P) {
  int b = blockIdx.x, c = blockIdx.y, dg = blockIdx.z, t = threadIdx.x;
  int d = dg * 256 + t;
  float lr = lam[d], li = lam[HIDC + d];
  float hr = P[(((long)b * NCH + c) * 2) * HIDC + d];
  float hi = P[(((long)b * NCH + c) * 2 + 1) * HIDC + d];
  __hip_bfloat16* ur = u + ((long)(b * L_SZ + c * LCH)) * NCOL + d;
  __hip_bfloat16* ui = ur + HIDC;
  const float* mrow = mask + b * L_SZ + c * LCH;
  for (int l = 0; l < LCH; l++) {
    float xr = __bfloat162float(ur[(long)l * NCOL]);
    float xi = __bfloat162float(ui[(long)l * NCOL]);
    int gl = c * LCH + l;
    float g = (gl > 0) ? mrow[l - 1] : 0.f;
    float nr = xr + g * (lr * hr - li * hi);
    float ni = xi + g * (lr * hi + li * hr);
    hr = nr; hi = ni;
    ur[(long)l * NCOL] = __float2bfloat16(hr);
    ui[(long)l * NCOL] = __float2bfloat16(hi);
  }
}

// ---------------- LayerNorm over D=512, in place on d_out ----------------
__global__ __launch_bounds__(256) void k_ln(float* __restrict__ y,
                                            const float* __restrict__ lnw,
                                            const float* __restrict__ lnb) {
  int row = blockIdx.x, t = threadIdx.x;
  float2 v = ((const float2*)(y + (long)row * DM))[t];
  float s = v.x + v.y;
  float q = v.x * v.x + v.y * v.y;
  for (int off = 32; off; off >>= 1) { s += __shfl_down(s, off); q += __shfl_down(q, off); }
  __shared__ float ss[4], sq[4];
  int w = t >> 6, lane = t & 63;
  if (lane == 0) { ss[w] = s; sq[w] = q; }
  __syncthreads();
  if (t == 0) {
    float S = ss[0] + ss[1] + ss[2] + ss[3];
    float Q = sq[0] + sq[1] + sq[2] + sq[3];
    float mu = S / (float)DM;
    float var = Q / (float)DM - mu * mu;
    ss[0] = mu; sq[0] = rsqrtf(var + 1e-5f);
  }
  __syncthreads();
  float mu = ss[0], rstd = sq[0];
  float2 o;
  o.x = (v.x - mu) * rstd * lnw[2 * t]     + lnb[2 * t];
  o.y = (v.y - mu) * rstd * lnw[2 * t + 1] + lnb[2 * t + 1];
  ((float2*)(y + (long)row * DM))[t] = o;
}

// ---------------- launch ----------------
extern "C" void kernel_launch(void* const* d_in, const int* in_sizes, int n_in,
                              void* d_out, int out_size, void* d_ws, size_t ws_size,
                              hipStream_t stream) {
  (void)in_sizes; (void)n_in; (void)out_size; (void)ws_size;
  const float* x         = (const float*)d_in[0];
  const float* mask      = (const float*)d_in[1];
  const float* nu_log    = (const float*)d_in[2];
  const float* theta_log = (const float*)d_in[3];
  const float* gamma_log = (const float*)d_in[4];
  const float* W_in_r    = (const float*)d_in[5];
  const float* W_in_i    = (const float*)d_in[6];
  const float* b_in_r    = (const float*)d_in[7];
  const float* b_in_i    = (const float*)d_in[8];
  const float* W_out_r   = (const float*)d_in[9];
  const float* W_out_i   = (const float*)d_in[10];
  const float* b_out_r   = (const float*)d_in[11];
  const float* ln_w      = (const float*)d_in[13];
  const float* ln_b      = (const float*)d_in[14];

  char* ws = (char*)d_ws;
  unsigned short* ubuf = (unsigned short*)(ws);              // 67,108,864
  unsigned short* xb   = (unsigned short*)(ws + 67108864);   // 16,777,216
  unsigned short* W1b  = (unsigned short*)(ws + 83886080);   // 2,097,152
  unsigned short* W2b  = (unsigned short*)(ws + 85983232);   // 2,097,152
  float* b1   = (float*)(ws + 88080384);                     // 8,192
  float* lam  = (float*)(ws + 88088576);                     // 8,192
  float* Ebuf = (float*)(ws + 88096768);                     // 1,048,576
  float* Pbuf = (float*)(ws + 89145344);                     // 1,048,576

  const int LDS1 = 2 * 2 * 256 * 64 * 2;                     // 131072 (8-phase)
  const int LDS2 = 3 * (128 + 128) * 32 * 2;                 // 49152 (MF=4)
  hipFuncSetAttribute((const void*)gemm1_8ph,
                      hipFuncAttributeMaxDynamicSharedMemorySize, LDS1);
  hipFuncSetAttribute((const void*)gemm_pipe<4, 0, 1, 2>,
                      hipFuncAttributeMaxDynamicSharedMemorySize, LDS2);

  k_cvt_x  <<<8192, 256, 0, stream>>>(x, xb);
  k_prep_w1<<<4096, 256, 0, stream>>>(W_in_r, W_in_i, b_in_r, b_in_i, gamma_log, W1b, b1);
  k_prep_w2<<<4096, 256, 0, stream>>>(W_out_r, W_out_i, W2b);
  k_prep_lam<<<4, 256, 0, stream>>>(nu_log, theta_log, lam);

  // GEMM1 (8-phase): u = xb @ W1b^T + b1 -> bf16 ubuf; grid 64x8 = 512 WGs
  gemm1_8ph<<<512, 512, LDS1, stream>>>(xb, W1b, ubuf, b1);

  // chunked linear-recurrence scan, in place on ubuf
  k_scan_local<<<dim3(B_SZ, NCH, HIDC / 256), 256, 0, stream>>>(
      (const __hip_bfloat16*)ubuf, lam, mask, Ebuf);
  k_scan_carry<<<32, 256, 0, stream>>>(Ebuf, lam, Pbuf);
  k_scan_final<<<dim3(B_SZ, NCH, HIDC / 256), 256, 0, stream>>>(
      (__hip_bfloat16*)ubuf, lam, mask, Pbuf);

  // GEMM2 (v5): out = h @ W2b^T + b_out_r + xb -> fp32 d_out; 512 WGs
  gemm_pipe<4, 0, 1, 2><<<512, 256, LDS2, stream>>>(
      ubuf, W2b, d_out, b_out_r, xb, NROW, DM, NCOL);

  // LayerNorm in place on d_out
  k_ln<<<NROW, 256, 0, stream>>>((float*)d_out, ln_w, ln_b);
}

// Round 7
// 179.172 us; speedup vs baseline: 1.0868x; 1.0868x over previous
//
#include <hip/hip_runtime.h>
#include <hip/hip_bf16.h>

// Problem constants
#define B_SZ 8
#define L_SZ 2048
#define DM   512
#define HIDC 1024            // complex hidden channels
#define NROW (B_SZ*L_SZ)     // 16384
#define NCOL (2*HIDC)        // 2048 (interleaved: col 2d = re_d, 2d+1 = im_d)
#define LCH  128             // scan chunk length
#define NCH  (L_SZ/LCH)      // 16 chunks

typedef __attribute__((ext_vector_type(8))) short bf16x8;
typedef __attribute__((ext_vector_type(4))) float f32x4;

typedef __attribute__((address_space(1))) const void gvoid_t;
typedef __attribute__((address_space(3))) void lvoid_t;

__device__ __forceinline__ void gload_lds16(const void* g, void* l) {
  __builtin_amdgcn_global_load_lds((gvoid_t*)g, (lvoid_t*)l, 16, 0, 0);
}

__device__ __forceinline__ unsigned short f2bf(float v) {
  return __builtin_bit_cast(unsigned short, __float2bfloat16(v));
}
__device__ __forceinline__ float bf2f(unsigned short u) {
  return __bfloat162float(__builtin_bit_cast(__hip_bfloat16, u));
}

// ---------------- prep kernels ----------------
__global__ void k_cvt_x(const float* __restrict__ x, unsigned short* __restrict__ xb) {
  long i = (long)blockIdx.x * 256 + threadIdx.x;
  float4 v = ((const float4*)x)[i];
  ushort4 o;
  o.x = f2bf(v.x); o.y = f2bf(v.y); o.z = f2bf(v.z); o.w = f2bf(v.w);
  ((ushort4*)xb)[i] = o;
}

// merged prep: W1b (interleaved rows), W2b (interleaved cols), lam
__global__ void k_prep_all(const float* __restrict__ Wr,  const float* __restrict__ Wi,
                           const float* __restrict__ br,  const float* __restrict__ bi,
                           const float* __restrict__ gamma_log,
                           const float* __restrict__ Wor, const float* __restrict__ Woi,
                           const float* __restrict__ nu_log, const float* __restrict__ theta_log,
                           unsigned short* __restrict__ W1b, float* __restrict__ b1,
                           unsigned short* __restrict__ W2b, float* __restrict__ lam) {
  int bid = blockIdx.x, t = threadIdx.x;
  if (bid < 4096) {                       // W1b[n][k], n=2d(+1): re/im of channel d, scaled by gamma
    long idx = (long)bid * 256 + t;       // 2048*512
    int n = (int)(idx >> 9), k = (int)(idx & 511);
    int d = n >> 1;
    float g = __expf(gamma_log[d]);
    float w = (n & 1) ? Wi[(long)d * DM + k] : Wr[(long)d * DM + k];
    W1b[idx] = f2bf(g * w);
    if (k == 0) b1[n] = g * ((n & 1) ? bi[d] : br[d]);
  } else if (bid < 8192) {                // W2b[e][k], k=2d: Wor[e][d], k=2d+1: -Woi[e][d]
    long idx = (long)(bid - 4096) * 256 + t;  // 512*2048
    int e = (int)(idx >> 11), k = (int)(idx & 2047);
    int d = k >> 1;
    float w = (k & 1) ? -Woi[(long)e * HIDC + d] : Wor[(long)e * HIDC + d];
    W2b[idx] = f2bf(w);
  } else {                                // lam
    int d = (bid - 8192) * 256 + t;
    if (d < HIDC) {
      float nu = __expf(nu_log[d]);
      float th = __expf(theta_log[d]);
      float mag = __expf(-nu);
      lam[d]        = mag * cosf(th);
      lam[HIDC + d] = mag * sinf(th);
    }
  }
}

// ============ GEMM1 (v5 structure, MF=8) + fused local-scan epilogue ============
// u = xb @ W1b^T + b1 -> bf16 ubuf [16384][2048 interleaved], AND per-block
// local-scan chunk-end values E (scan pass 1) computed from the bf16-rounded
// tile held in LDS. Main loop identical to R5's proven gemm_pipe<8,...>:
// BM=256 BN=128 BK=32, 4 waves (2x2), triple-buffer, counted vmcnt(6),
// both-sides swizzle slot^((row>>1)&3), XCD m-band blocking (LGY=4).
// New: K-rotation stagger rot=((blockIdx>>8)&1)*8 so co-resident blocks
// process K-tiles in anti-phase (accumulation order-invariant).
__global__ __launch_bounds__(256, 2)
void gemm1_fused(const unsigned short* __restrict__ A, const unsigned short* __restrict__ Bw,
                 unsigned short* __restrict__ C, const float* __restrict__ bias,
                 const float* __restrict__ lam, const float* __restrict__ mask,
                 float2* __restrict__ E2) {
  constexpr int K = DM, N = NCOL;         // 512, 2048
  constexpr int ABUF = 256 * 32, BBUF = 128 * 32, NT = K / 32;  // NT=16
  extern __shared__ unsigned short lds[];
  unsigned short* As = lds;               // 3 * ABUF
  unsigned short* Bs = lds + 3 * ABUF;    // 3 * BBUF

  const int tid  = threadIdx.x;
  const int w    = tid >> 6, lane = tid & 63;
  const int wr   = w >> 1,   wc   = w & 1;
  const int fr   = lane & 15, lq  = lane >> 4;

  // XCD 2-D blocking: 1024 blocks = 64 mt x 16 nt, XCD owns 8 mt x all nt
  const int xcd  = blockIdx.x & 7;
  const int idx  = blockIdx.x >> 3;
  const int mt   = xcd * 8 + (idx >> 4);
  const int nt   = idx & 15;
  const long m0  = (long)mt * 256;
  const long n0  = (long)nt * 128;
  const int rot  = ((blockIdx.x >> 8) & 1) << 3;   // anti-phase K order

  const int srow  = tid >> 2;
  const int gslot = (tid & 3) ^ ((tid >> 3) & 3);
  const unsigned short* Agp = A  + (m0 + srow) * (long)K + gslot * 8;
  const unsigned short* Bgp = Bw + (n0 + srow) * (long)K + gslot * 8;
  const int ldst = tid * 8;

#define STAGE(t, b) {                                                        \
    long ko = (long)(((t) + rot) & (NT - 1)) * 32;                           \
    _Pragma("unroll")                                                        \
    for (int u = 0; u < 4; u++)                                              \
      gload_lds16(Agp + ko + (long)(u * 64) * K,                             \
                  &As[(b) * ABUF + u * 2048 + ldst]);                        \
    gload_lds16(Bgp + ko,                  &Bs[(b) * BBUF +        ldst]);   \
    gload_lds16(Bgp + ko + (long)64 * K,   &Bs[(b) * BBUF + 2048 + ldst]); }

  const int sx = (lq ^ ((fr >> 1) & 3)) << 3;

  f32x4 acc[8][4] = {};

  STAGE(0, 0);
  STAGE(1, 1);
  asm volatile("s_waitcnt vmcnt(6)" ::: "memory");
  __builtin_amdgcn_s_barrier();
  __builtin_amdgcn_sched_barrier(0);

  int cb = 0, bt2 = 2;
  for (int t = 0; t < NT; ++t) {
    if (t + 2 < NT) STAGE(t + 2, bt2);

    const unsigned short* Ab = As + cb * ABUF;
    const unsigned short* Bb = Bs + cb * BBUF;
    bf16x8 fa[8], fb[4];
#pragma unroll
    for (int m = 0; m < 8; m++)
      fa[m] = *(const bf16x8*)&Ab[(wr * 128 + m * 16 + fr) * 32 + sx];
#pragma unroll
    for (int n = 0; n < 4; n++)
      fb[n] = *(const bf16x8*)&Bb[(wc * 64 + n * 16 + fr) * 32 + sx];
    __builtin_amdgcn_s_setprio(1);
#pragma unroll
    for (int m = 0; m < 8; m++)
#pragma unroll
      for (int n = 0; n < 4; n++)
        acc[m][n] = __builtin_amdgcn_mfma_f32_16x16x32_bf16(fa[m], fb[n], acc[m][n], 0, 0, 0);
    __builtin_amdgcn_s_setprio(0);

    if (t < NT - 1) {
      if (t + 2 < NT) { asm volatile("s_waitcnt vmcnt(6)" ::: "memory"); }
      else            { asm volatile("s_waitcnt vmcnt(0)" ::: "memory"); }
      __builtin_amdgcn_s_barrier();
      __builtin_amdgcn_sched_barrier(0);
    }
    cb  = (cb  == 2) ? 0 : cb + 1;
    bt2 = (bt2 == 2) ? 0 : bt2 + 1;
  }
#undef STAGE

  // ---- epilogue 1: write C (global) and the bf16 tile to LDS [256][pitch 130]
  __syncthreads();                        // all waves done reading As/Bs
  const int cr0 = lq * 4, cc = fr;
#pragma unroll
  for (int m = 0; m < 8; m++) {
#pragma unroll
    for (int n = 0; n < 4; n++) {
      int coll = wc * 64 + n * 16 + cc;
      long col = n0 + coll;
      float bv = bias[col];
#pragma unroll
      for (int r = 0; r < 4; r++) {
        int rowl = wr * 128 + m * 16 + cr0 + r;
        unsigned short us = f2bf(acc[m][n][r] + bv);
        C[(m0 + rowl) * (long)N + col] = us;
        lds[rowl * 130 + coll] = us;
      }
    }
  }
  __syncthreads();

  // ---- epilogue 2: fused scan pass 1 (local chunk scans -> E)
  // block tile = rows [m0, m0+256) = 2 chunks of batch b, cols = 64 complex ch
  if (tid < 128) {
    const int chunk = tid >> 6, ch = tid & 63;
    const int dglob = (int)(n0 >> 1) + ch;
    const int bidx  = (int)(m0 >> 11);
    const int l0    = (int)(m0 & 2047);
    const int cglob = (l0 >> 7) + chunk;
    const float lr = lam[dglob], li = lam[HIDC + dglob];
    const float* mrow = mask + bidx * L_SZ + l0 + chunk * 128;
    float er = 0.f, ei = 0.f;
    for (int j = 0; j < 128; j++) {
      unsigned int v = *(const unsigned int*)&lds[(chunk * 128 + j) * 130 + 2 * ch];
      float xr = bf2f((unsigned short)(v & 0xffffu));
      float xi = bf2f((unsigned short)(v >> 16));
      float g = (j > 0) ? mrow[j - 1] : 0.f;    // local carry starts at 0
      float nr = xr + g * (lr * er - li * ei);
      float ni = xi + g * (lr * ei + li * er);
      er = nr; ei = ni;
    }
    E2[((long)bidx * NCH + cglob) * HIDC + dglob] = make_float2(er, ei);
  }
}

// ---------------- GEMM2: pipelined v5 (MF=4) + K-stagger ----------------
template<int MF, int OUT_BF16, int HAS_RESID, int LGY>
__global__ __launch_bounds__(256, 2)
void gemm_pipe(const unsigned short* __restrict__ A, const unsigned short* __restrict__ Bw,
               void* __restrict__ C, const float* __restrict__ bias,
               const unsigned short* __restrict__ resid, int M, int N, int K) {
  constexpr int BM     = MF * 32;
  constexpr int AUNITS = MF / 2;
  constexpr int LT     = AUNITS + 2;
  constexpr int ABUF   = BM * 32;
  constexpr int BBUF   = 128 * 32;

  extern __shared__ unsigned short lds[];
  unsigned short* As = lds;
  unsigned short* Bs = lds + 3 * ABUF;

  const int tid  = threadIdx.x;
  const int w    = tid >> 6, lane = tid & 63;
  const int wr   = w >> 1,   wc   = w & 1;
  const int fr   = lane & 15, lq  = lane >> 4;

  const int gx   = M / BM;
  const int xcd  = blockIdx.x & 7;
  const int idx  = blockIdx.x >> 3;
  const int mt   = xcd * (gx >> 3) + (idx >> LGY);
  const int nt   = idx & ((1 << LGY) - 1);
  const long m0  = (long)mt * BM;
  const long n0  = (long)nt * 128;

  const int srow  = tid >> 2;
  const int gslot = (tid & 3) ^ ((tid >> 3) & 3);
  const unsigned short* Agp = A  + (m0 + srow) * (long)K + gslot * 8;
  const unsigned short* Bgp = Bw + (n0 + srow) * (long)K + gslot * 8;
  const int ldst = tid * 8;
  const int NT   = K >> 5;
  const int rot  = ((blockIdx.x >> 8) & 1) * (NT >> 1);

#define STAGE(t, b) {                                                        \
    long ko = (long)(((t) + rot) & (NT - 1)) * 32;                           \
    _Pragma("unroll")                                                        \
    for (int u = 0; u < AUNITS; u++)                                         \
      gload_lds16(Agp + ko + (long)(u * 64) * K,                             \
                  &As[(b) * ABUF + u * 2048 + ldst]);                        \
    gload_lds16(Bgp + ko,                  &Bs[(b) * BBUF +        ldst]);   \
    gload_lds16(Bgp + ko + (long)64 * K,   &Bs[(b) * BBUF + 2048 + ldst]); }

  const int sx = (lq ^ ((fr >> 1) & 3)) << 3;

  f32x4 acc[MF][4] = {};

  STAGE(0, 0);
  STAGE(1, 1);
  if constexpr (LT == 6) asm volatile("s_waitcnt vmcnt(6)" ::: "memory");
  else                   asm volatile("s_waitcnt vmcnt(4)" ::: "memory");
  __builtin_amdgcn_s_barrier();
  __builtin_amdgcn_sched_barrier(0);

  int cb = 0, bt2 = 2;
  for (int t = 0; t < NT; ++t) {
    if (t + 2 < NT) STAGE(t + 2, bt2);

    const unsigned short* Ab = As + cb * ABUF;
    const unsigned short* Bb = Bs + cb * BBUF;
    bf16x8 fa[MF], fb[4];
#pragma unroll
    for (int m = 0; m < MF; m++)
      fa[m] = *(const bf16x8*)&Ab[(wr * (MF * 16) + m * 16 + fr) * 32 + sx];
#pragma unroll
    for (int n = 0; n < 4; n++)
      fb[n] = *(const bf16x8*)&Bb[(wc * 64 + n * 16 + fr) * 32 + sx];
    __builtin_amdgcn_s_setprio(1);
#pragma unroll
    for (int m = 0; m < MF; m++)
#pragma unroll
      for (int n = 0; n < 4; n++)
        acc[m][n] = __builtin_amdgcn_mfma_f32_16x16x32_bf16(fa[m], fb[n], acc[m][n], 0, 0, 0);
    __builtin_amdgcn_s_setprio(0);

    if (t < NT - 1) {
      if (t + 2 < NT) {
        if constexpr (LT == 6) asm volatile("s_waitcnt vmcnt(6)" ::: "memory");
        else                   asm volatile("s_waitcnt vmcnt(4)" ::: "memory");
      } else {
        asm volatile("s_waitcnt vmcnt(0)" ::: "memory");
      }
      __builtin_amdgcn_s_barrier();
      __builtin_amdgcn_sched_barrier(0);
    }
    cb  = (cb  == 2) ? 0 : cb + 1;
    bt2 = (bt2 == 2) ? 0 : bt2 + 1;
  }
#undef STAGE

  const int cr0 = lq * 4, cc = fr;
#pragma unroll
  for (int m = 0; m < MF; m++) {
#pragma unroll
    for (int n = 0; n < 4; n++) {
      long col = n0 + wc * 64 + n * 16 + cc;
      float bv = bias[col];
#pragma unroll
      for (int r = 0; r < 4; r++) {
        long row = m0 + wr * (MF * 16) + m * 16 + cr0 + r;
        float v = acc[m][n][r] + bv;
        if (HAS_RESID) v += bf2f(resid[row * (long)N + col]);
        if (OUT_BF16)
          ((unsigned short*)C)[row * (long)N + col] = f2bf(v);
        else
          ((float*)C)[row * (long)N + col] = v;
      }
    }
  }
}

// -------- scan pass 2: chunk-carry scan over E (float2, interleaved) --------
__global__ void k_scan_carry(const float2* __restrict__ E2, const float* __restrict__ lam,
                             float2* __restrict__ P2) {
  int idx = blockIdx.x * 256 + threadIdx.x;   // 8192 = B * HIDC
  int b = idx >> 10, d = idx & (HIDC - 1);
  float lr = lam[d], li = lam[HIDC + d];
  float ar = lr, ai = li;                     // lam^128 via 7 squarings
  for (int s = 0; s < 7; s++) { float nr = ar * ar - ai * ai; float ni = 2.f * ar * ai; ar = nr; ai = ni; }
  float pr = 0.f, pi = 0.f;
  for (int c = 0; c < NCH; c++) {
    P2[((long)b * NCH + c) * HIDC + d] = make_float2(pr, pi);
    float2 e = E2[((long)b * NCH + c) * HIDC + d];
    float nr = e.x + ar * pr - ai * pi;
    float ni = e.y + ar * pi + ai * pr;
    pr = nr; pi = ni;
  }
}

// -------- scan pass 3: finalize with carry-in, in place on ubuf (u32 pairs) --------
__global__ void k_scan_final(unsigned int* __restrict__ u,    // ubuf as u32[16384][1024]
                             const float* __restrict__ lam,
                             const float* __restrict__ mask,
                             const float2* __restrict__ P2) {
  int b = blockIdx.x, c = blockIdx.y, dg = blockIdx.z, t = threadIdx.x;
  int d = dg * 256 + t;
  float lr = lam[d], li = lam[HIDC + d];
  float2 pc = P2[((long)b * NCH + c) * HIDC + d];
  float hr = pc.x, hi = pc.y;
  unsigned int* up = u + ((long)(b * L_SZ + c * LCH)) * HIDC + d;
  const float* mrow = mask + b * L_SZ + c * LCH;
  for (int l = 0; l < LCH; l++) {
    unsigned int v = up[(long)l * HIDC];
    float xr = bf2f((unsigned short)(v & 0xffffu));
    float xi = bf2f((unsigned short)(v >> 16));
    float g = (c * LCH + l > 0) ? mrow[l - 1] : 0.f;
    float nr = xr + g * (lr * hr - li * hi);
    float ni = xi + g * (lr * hi + li * hr);
    hr = nr; hi = ni;
    up[(long)l * HIDC] = (unsigned int)f2bf(hr) | ((unsigned int)f2bf(hi) << 16);
  }
}

// ---------------- LayerNorm over D=512, in place on d_out ----------------
__global__ __launch_bounds__(256) void k_ln(float* __restrict__ y,
                                            const float* __restrict__ lnw,
                                            const float* __restrict__ lnb) {
  int row = blockIdx.x, t = threadIdx.x;
  float2 v = ((const float2*)(y + (long)row * DM))[t];
  float s = v.x + v.y;
  float q = v.x * v.x + v.y * v.y;
  for (int off = 32; off; off >>= 1) { s += __shfl_down(s, off); q += __shfl_down(q, off); }
  __shared__ float ss[4], sq[4];
  int w = t >> 6, lane = t & 63;
  if (lane == 0) { ss[w] = s; sq[w] = q; }
  __syncthreads();
  if (t == 0) {
    float S = ss[0] + ss[1] + ss[2] + ss[3];
    float Q = sq[0] + sq[1] + sq[2] + sq[3];
    float mu = S / (float)DM;
    float var = Q / (float)DM - mu * mu;
    ss[0] = mu; sq[0] = rsqrtf(var + 1e-5f);
  }
  __syncthreads();
  float mu = ss[0], rstd = sq[0];
  float2 o;
  o.x = (v.x - mu) * rstd * lnw[2 * t]     + lnb[2 * t];
  o.y = (v.y - mu) * rstd * lnw[2 * t + 1] + lnb[2 * t + 1];
  ((float2*)(y + (long)row * DM))[t] = o;
}

// ---------------- launch ----------------
extern "C" void kernel_launch(void* const* d_in, const int* in_sizes, int n_in,
                              void* d_out, int out_size, void* d_ws, size_t ws_size,
                              hipStream_t stream) {
  (void)in_sizes; (void)n_in; (void)out_size; (void)ws_size;
  const float* x         = (const float*)d_in[0];
  const float* mask      = (const float*)d_in[1];
  const float* nu_log    = (const float*)d_in[2];
  const float* theta_log = (const float*)d_in[3];
  const float* gamma_log = (const float*)d_in[4];
  const float* W_in_r    = (const float*)d_in[5];
  const float* W_in_i    = (const float*)d_in[6];
  const float* b_in_r    = (const float*)d_in[7];
  const float* b_in_i    = (const float*)d_in[8];
  const float* W_out_r   = (const float*)d_in[9];
  const float* W_out_i   = (const float*)d_in[10];
  const float* b_out_r   = (const float*)d_in[11];
  const float* ln_w      = (const float*)d_in[13];
  const float* ln_b      = (const float*)d_in[14];

  char* ws = (char*)d_ws;
  unsigned short* ubuf = (unsigned short*)(ws);              // 67,108,864
  unsigned short* xb   = (unsigned short*)(ws + 67108864);   // 16,777,216
  unsigned short* W1b  = (unsigned short*)(ws + 83886080);   // 2,097,152
  unsigned short* W2b  = (unsigned short*)(ws + 85983232);   // 2,097,152
  float*  b1   = (float*)(ws + 88080384);                    // 8,192
  float*  lam  = (float*)(ws + 88088576);                    // 8,192
  float2* Ebuf = (float2*)(ws + 88096768);                   // 1,048,576
  float2* Pbuf = (float2*)(ws + 89145344);                   // 1,048,576

  const int LDS1 = 3 * (256 + 128) * 32 * 2;                 // 73728 (gemm1_fused)
  const int LDS2 = 3 * (128 + 128) * 32 * 2;                 // 49152 (MF=4)
  hipFuncSetAttribute((const void*)gemm1_fused,
                      hipFuncAttributeMaxDynamicSharedMemorySize, LDS1);
  hipFuncSetAttribute((const void*)gemm_pipe<4, 0, 1, 2>,
                      hipFuncAttributeMaxDynamicSharedMemorySize, LDS2);

  k_cvt_x   <<<8192, 256, 0, stream>>>(x, xb);
  k_prep_all<<<8196, 256, 0, stream>>>(W_in_r, W_in_i, b_in_r, b_in_i, gamma_log,
                                       W_out_r, W_out_i, nu_log, theta_log,
                                       W1b, b1, W2b, lam);

  // GEMM1 + fused scan pass 1: 1024 WGs
  gemm1_fused<<<1024, 256, LDS1, stream>>>(xb, W1b, ubuf, b1, lam, mask, Ebuf);

  // scan passes 2, 3
  k_scan_carry<<<32, 256, 0, stream>>>(Ebuf, lam, Pbuf);
  k_scan_final<<<dim3(B_SZ, NCH, HIDC / 256), 256, 0, stream>>>(
      (unsigned int*)ubuf, lam, mask, Pbuf);

  // GEMM2: out = h @ W2b^T + b_out_r + xb -> fp32 d_out; 512 WGs
  gemm_pipe<4, 0, 1, 2><<<512, 256, LDS2, stream>>>(
      ubuf, W2b, d_out, b_out_r, xb, NROW, DM, NCOL);

  // LayerNorm in place on d_out
  k_ln<<<NROW, 256, 0, stream>>>((float*)d_out, ln_w, ln_b);
}

// Round 8
// 170.646 us; speedup vs baseline: 1.1411x; 1.0500x over previous
//
#include <hip/hip_runtime.h>
#include <hip/hip_bf16.h>

// Problem constants
#define B_SZ 8
#define L_SZ 2048
#define DM   512
#define HIDC 1024            // complex hidden channels
#define NROW (B_SZ*L_SZ)     // 16384
#define NCOL (2*HIDC)        // 2048 (interleaved: col 2d = re_d, 2d+1 = im_d)
#define LCH  128             // scan chunk length
#define NCH  (L_SZ/LCH)      // 16 chunks

typedef __attribute__((ext_vector_type(8))) short bf16x8;
typedef __attribute__((ext_vector_type(4))) float f32x4;

typedef __attribute__((address_space(1))) const void gvoid_t;
typedef __attribute__((address_space(3))) void lvoid_t;

__device__ __forceinline__ void gload_lds16(const void* g, void* l) {
  __builtin_amdgcn_global_load_lds((gvoid_t*)g, (lvoid_t*)l, 16, 0, 0);
}

__device__ __forceinline__ unsigned short f2bf(float v) {
  return __builtin_bit_cast(unsigned short, __float2bfloat16(v));
}
__device__ __forceinline__ float bf2f(unsigned short u) {
  return __bfloat162float(__builtin_bit_cast(__hip_bfloat16, u));
}

// ---------------- prep kernels ----------------
__global__ void k_cvt_x(const float* __restrict__ x, unsigned short* __restrict__ xb) {
  long i = (long)blockIdx.x * 256 + threadIdx.x;
  float4 v = ((const float4*)x)[i];
  ushort4 o;
  o.x = f2bf(v.x); o.y = f2bf(v.y); o.z = f2bf(v.z); o.w = f2bf(v.w);
  ((ushort4*)xb)[i] = o;
}

// merged prep: W1b (interleaved rows), W2b (interleaved cols), lam
__global__ void k_prep_all(const float* __restrict__ Wr,  const float* __restrict__ Wi,
                           const float* __restrict__ br,  const float* __restrict__ bi,
                           const float* __restrict__ gamma_log,
                           const float* __restrict__ Wor, const float* __restrict__ Woi,
                           const float* __restrict__ nu_log, const float* __restrict__ theta_log,
                           unsigned short* __restrict__ W1b, float* __restrict__ b1,
                           unsigned short* __restrict__ W2b, float* __restrict__ lam) {
  int bid = blockIdx.x, t = threadIdx.x;
  if (bid < 4096) {                       // W1b[n][k], n=2d(+1): re/im of channel d, scaled by gamma
    long idx = (long)bid * 256 + t;       // 2048*512
    int n = (int)(idx >> 9), k = (int)(idx & 511);
    int d = n >> 1;
    float g = __expf(gamma_log[d]);
    float w = (n & 1) ? Wi[(long)d * DM + k] : Wr[(long)d * DM + k];
    W1b[idx] = f2bf(g * w);
    if (k == 0) b1[n] = g * ((n & 1) ? bi[d] : br[d]);
  } else if (bid < 8192) {                // W2b[e][k], k=2d: Wor[e][d], k=2d+1: -Woi[e][d]
    long idx = (long)(bid - 4096) * 256 + t;  // 512*2048
    int e = (int)(idx >> 11), k = (int)(idx & 2047);
    int d = k >> 1;
    float w = (k & 1) ? -Woi[(long)e * HIDC + d] : Wor[(long)e * HIDC + d];
    W2b[idx] = f2bf(w);
  } else {                                // lam
    int d = (bid - 8192) * 256 + t;
    if (d < HIDC) {
      float nu = __expf(nu_log[d]);
      float th = __expf(theta_log[d]);
      float mag = __expf(-nu);
      lam[d]        = mag * cosf(th);
      lam[HIDC + d] = mag * sinf(th);
    }
  }
}

// ============ GEMM1 (v5 structure, MF=8) + fused local-scan epilogue ============
// u = xb @ W1b^T + b1 -> bf16 ubuf [16384][2048 interleaved], AND scan pass 1
// chunk-end values E computed from the bf16-rounded tile held in LDS.
// Core identical to R5/R7 proven loop. Epilogue changes (R7 post-mortem):
//  - LDS tile pitch 130 -> 132 ushorts (264B): lq row-groups now 8 banks apart,
//    disjoint from the 8-bank fr span -> conflict-free writes; scan reads
//    (66j + lane)%32 -> 2/bank (free).
//  - local scan split into 2 x 64-step affine segments using all 256 threads:
//    h_end = B1 + A1*B0 where each segment computes (A = prod g*lam, B = local
//    end with zero init); seg1's first gate uses mrow[63] (chunk-local rule).
__global__ __launch_bounds__(256, 2)
void gemm1_fused(const unsigned short* __restrict__ A, const unsigned short* __restrict__ Bw,
                 unsigned short* __restrict__ C, const float* __restrict__ bias,
                 const float* __restrict__ lam, const float* __restrict__ mask,
                 float2* __restrict__ E2) {
  constexpr int K = DM, N = NCOL;         // 512, 2048
  constexpr int ABUF = 256 * 32, BBUF = 128 * 32, NT = K / 32;  // NT=16
  extern __shared__ unsigned short lds[];
  unsigned short* As = lds;               // 3 * ABUF
  unsigned short* Bs = lds + 3 * ABUF;    // 3 * BBUF

  const int tid  = threadIdx.x;
  const int w    = tid >> 6, lane = tid & 63;
  const int wr   = w >> 1,   wc   = w & 1;
  const int fr   = lane & 15, lq  = lane >> 4;

  // XCD 2-D blocking: 1024 blocks = 64 mt x 16 nt, XCD owns 8 mt x all nt
  const int xcd  = blockIdx.x & 7;
  const int idx  = blockIdx.x >> 3;
  const int mt   = xcd * 8 + (idx >> 4);
  const int nt   = idx & 15;
  const long m0  = (long)mt * 256;
  const long n0  = (long)nt * 128;
  const int rot  = ((blockIdx.x >> 8) & 1) << 3;   // anti-phase K order

  const int srow  = tid >> 2;
  const int gslot = (tid & 3) ^ ((tid >> 3) & 3);
  const unsigned short* Agp = A  + (m0 + srow) * (long)K + gslot * 8;
  const unsigned short* Bgp = Bw + (n0 + srow) * (long)K + gslot * 8;
  const int ldst = tid * 8;

#define STAGE(t, b) {                                                        \
    long ko = (long)(((t) + rot) & (NT - 1)) * 32;                           \
    _Pragma("unroll")                                                        \
    for (int u = 0; u < 4; u++)                                              \
      gload_lds16(Agp + ko + (long)(u * 64) * K,                             \
                  &As[(b) * ABUF + u * 2048 + ldst]);                        \
    gload_lds16(Bgp + ko,                  &Bs[(b) * BBUF +        ldst]);   \
    gload_lds16(Bgp + ko + (long)64 * K,   &Bs[(b) * BBUF + 2048 + ldst]); }

  const int sx = (lq ^ ((fr >> 1) & 3)) << 3;

  f32x4 acc[8][4] = {};

  STAGE(0, 0);
  STAGE(1, 1);
  asm volatile("s_waitcnt vmcnt(6)" ::: "memory");
  __builtin_amdgcn_s_barrier();
  __builtin_amdgcn_sched_barrier(0);

  int cb = 0, bt2 = 2;
  for (int t = 0; t < NT; ++t) {
    if (t + 2 < NT) STAGE(t + 2, bt2);

    const unsigned short* Ab = As + cb * ABUF;
    const unsigned short* Bb = Bs + cb * BBUF;
    bf16x8 fa[8], fb[4];
#pragma unroll
    for (int m = 0; m < 8; m++)
      fa[m] = *(const bf16x8*)&Ab[(wr * 128 + m * 16 + fr) * 32 + sx];
#pragma unroll
    for (int n = 0; n < 4; n++)
      fb[n] = *(const bf16x8*)&Bb[(wc * 64 + n * 16 + fr) * 32 + sx];
    __builtin_amdgcn_s_setprio(1);
#pragma unroll
    for (int m = 0; m < 8; m++)
#pragma unroll
      for (int n = 0; n < 4; n++)
        acc[m][n] = __builtin_amdgcn_mfma_f32_16x16x32_bf16(fa[m], fb[n], acc[m][n], 0, 0, 0);
    __builtin_amdgcn_s_setprio(0);

    if (t < NT - 1) {
      if (t + 2 < NT) { asm volatile("s_waitcnt vmcnt(6)" ::: "memory"); }
      else            { asm volatile("s_waitcnt vmcnt(0)" ::: "memory"); }
      __builtin_amdgcn_s_barrier();
      __builtin_amdgcn_sched_barrier(0);
    }
    cb  = (cb  == 2) ? 0 : cb + 1;
    bt2 = (bt2 == 2) ? 0 : bt2 + 1;
  }
#undef STAGE

  // ---- epilogue 1: write C (global) and the bf16 tile to LDS [256][pitch 132]
  __syncthreads();                        // all waves done reading As/Bs
  const int cr0 = lq * 4, cc = fr;
#pragma unroll
  for (int m = 0; m < 8; m++) {
#pragma unroll
    for (int n = 0; n < 4; n++) {
      int coll = wc * 64 + n * 16 + cc;
      long col = n0 + coll;
      float bv = bias[col];
#pragma unroll
      for (int r = 0; r < 4; r++) {
        int rowl = wr * 128 + m * 16 + cr0 + r;
        unsigned short us = f2bf(acc[m][n][r] + bv);
        C[(m0 + rowl) * (long)N + col] = us;
        lds[rowl * 132 + coll] = us;
      }
    }
  }
  __syncthreads();

  // ---- epilogue 2: fused scan pass 1, 2 x 64-step segments, all 256 threads
  {
    const int ch    = tid & 63;           // complex channel within tile
    const int seg   = (tid >> 6) & 1;
    const int chunk = tid >> 7;
    const int dglob = (int)(n0 >> 1) + ch;
    const int bidx  = (int)(m0 >> 11);
    const int l0    = (int)(m0 & 2047);
    const int cglob = (l0 >> 7) + chunk;
    const float lr = lam[dglob], li = lam[HIDC + dglob];
    const float* mrow = mask + bidx * L_SZ + l0 + chunk * 128;
    const unsigned int* ldsw = (const unsigned int*)lds;
    float ar = 1.f, ai = 0.f, brr = 0.f, bii = 0.f;
    const int j0 = seg * 64;
    for (int j = 0; j < 64; j++) {
      int jj = j0 + j;
      unsigned int v = ldsw[(chunk * 128 + jj) * 66 + ch];
      float xr = bf2f((unsigned short)(v & 0xffffu));
      float xi = bf2f((unsigned short)(v >> 16));
      float g = (jj > 0) ? mrow[jj - 1] : 0.f;
      float glr = g * lr, gli = g * li;
      float nbr = xr + glr * brr - gli * bii;
      float nbi = xi + glr * bii + gli * brr;
      float nar = glr * ar - gli * ai;
      float nai = glr * ai + gli * ar;
      brr = nbr; bii = nbi; ar = nar; ai = nai;
    }
    float2* comb = (float2*)(lds + 256 * 132);   // 128 float2
    if (seg == 0) comb[chunk * 64 + ch] = make_float2(brr, bii);
    __syncthreads();
    if (seg == 1) {
      float2 b0 = comb[chunk * 64 + ch];
      float er = brr + ar * b0.x - ai * b0.y;
      float ei = bii + ar * b0.y + ai * b0.x;
      E2[((long)bidx * NCH + cglob) * HIDC + dglob] = make_float2(er, ei);
    }
  }
}

// ============ GEMM2 + fused LayerNorm: full-row blocks ============
// out = LN(h @ W2b^T + b_out + resid) -> fp32 d_out [16384][512].
// BM=64, BN=512 (full row), BK=32; 512 thr = 8 waves, wave w owns cols
// [w*64, w*64+64) x all 64 rows (4m x 4n frags). Quad-buffered LDS (144KB),
// depth-3 prefetch for the K=2048 stream. W2b (2MB) is L2-resident per XCD.
//
// Stage = 5 gloads for waves 0-3 (1 A + 4 B slices), 4 for waves 4-7 (B only;
// B rows 0-127 staged by all 512 threads per call). vmcnt is per-wave:
//   steady (3 stages out): waves0-3 have 15, waves4-7 12 outstanding; uniform
//   vmcnt(8) retires >= all of stage t+1 for both. t+3==NT: vmcnt(4).
//   t+3==NT+1: vmcnt(0). WAR: STAGE(t+3) overwrites buf((t-1)&3), whose
//   ds_reads completed before the barrier ending iter t-1.
// Epilogue: v = acc+bias+resid; row stats via shfl_xor over the 16 fr-lanes,
// cross-wave via LDS (reused staging area after a barrier); normalize; store.
__global__ __launch_bounds__(512, 2)
void gemm2_ln(const unsigned short* __restrict__ A, const unsigned short* __restrict__ Bw,
              float* __restrict__ Out, const float* __restrict__ bias,
              const unsigned short* __restrict__ resid,
              const float* __restrict__ lnw, const float* __restrict__ lnb) {
  constexpr int K = NCOL;          // 2048
  constexpr int N = DM;            // 512
  constexpr int NT = K / 32;       // 64
  constexpr int ABUF = 64 * 32;    // 2048 ushorts
  constexpr int BBUF = 512 * 32;   // 16384 ushorts
  extern __shared__ unsigned short lds[];
  unsigned short* As = lds;                  // 4 * ABUF
  unsigned short* Bs = lds + 4 * ABUF;       // 4 * BBUF

  const int tid = threadIdx.x;
  const int w = tid >> 6, lane = tid & 63;
  const int fr = lane & 15, lq = lane >> 4;

  // 256 blocks: XCD owns 32 consecutive m-tiles (A band 8MB streamed once;
  // B 2MB L2-resident)
  const int xcd = blockIdx.x & 7;
  const int mt  = xcd * 32 + (blockIdx.x >> 3);
  const long m0 = (long)mt * 64;

  const int srowA = (tid & 255) >> 2;         // 0..63
  const int srowB = tid >> 2;                 // 0..127
  const int gslot = (tid & 3) ^ ((tid >> 3) & 3);
  const unsigned short* Agp = A  + (m0 + srowA) * (long)K + gslot * 8;
  const unsigned short* Bgp = Bw + (long)srowB * K + gslot * 8;
  const int ldst = tid * 8;

#define STAGE2(t, b) {                                                       \
    long ko = (long)(t) * 32;                                                \
    if (tid < 256) gload_lds16(Agp + ko, &As[(b) * ABUF + ldst]);            \
    _Pragma("unroll")                                                        \
    for (int u = 0; u < 4; u++)                                              \
      gload_lds16(Bgp + ko + (long)(u * 128) * K,                            \
                  &Bs[(b) * BBUF + u * 4096 + ldst]); }

  const int sx = (lq ^ ((fr >> 1) & 3)) << 3;

  f32x4 acc[4][4] = {};

  STAGE2(0, 0); STAGE2(1, 1); STAGE2(2, 2);
  asm volatile("s_waitcnt vmcnt(8)" ::: "memory");
  __builtin_amdgcn_s_barrier();
  __builtin_amdgcn_sched_barrier(0);

  for (int t = 0; t < NT; ++t) {
    if (t + 3 < NT) STAGE2(t + 3, (t + 3) & 3);

    const unsigned short* Ab = As + (t & 3) * ABUF;
    const unsigned short* Bb = Bs + (t & 3) * BBUF;
    bf16x8 fa[4], fb[4];
#pragma unroll
    for (int m = 0; m < 4; m++)
      fa[m] = *(const bf16x8*)&Ab[(m * 16 + fr) * 32 + sx];
#pragma unroll
    for (int n = 0; n < 4; n++)
      fb[n] = *(const bf16x8*)&Bb[(w * 64 + n * 16 + fr) * 32 + sx];
    __builtin_amdgcn_s_setprio(1);
#pragma unroll
    for (int m = 0; m < 4; m++)
#pragma unroll
      for (int n = 0; n < 4; n++)
        acc[m][n] = __builtin_amdgcn_mfma_f32_16x16x32_bf16(fa[m], fb[n], acc[m][n], 0, 0, 0);
    __builtin_amdgcn_s_setprio(0);

    if (t < NT - 1) {
      if (t + 3 < NT)      { asm volatile("s_waitcnt vmcnt(8)" ::: "memory"); }
      else if (t + 2 < NT) { asm volatile("s_waitcnt vmcnt(4)" ::: "memory"); }
      else                 { asm volatile("s_waitcnt vmcnt(0)" ::: "memory"); }
      __builtin_amdgcn_s_barrier();
      __builtin_amdgcn_sched_barrier(0);
    }
  }
#undef STAGE2

  // ---- fused LN epilogue ----
  __syncthreads();                  // all LDS reads done -> reuse as scratch
  float* rs   = (float*)lds;        // [64][8] row partial sums
  float* qs   = rs + 512;           // [64][8] row partial sumsq
  float* mus  = qs + 512;           // [64]
  float* rsds = mus + 64;           // [64]

  const int cr0 = lq * 4;
  float bv[4], lw[4], lb[4];
#pragma unroll
  for (int n = 0; n < 4; n++) {
    int col = w * 64 + n * 16 + fr;
    bv[n] = bias[col]; lw[n] = lnw[col]; lb[n] = lnb[col];
  }

  float ps[4][4], pq[4][4];
#pragma unroll
  for (int m = 0; m < 4; m++)
#pragma unroll
    for (int r = 0; r < 4; r++) { ps[m][r] = 0.f; pq[m][r] = 0.f; }

#pragma unroll
  for (int m = 0; m < 4; m++) {
#pragma unroll
    for (int n = 0; n < 4; n++) {
      int col = w * 64 + n * 16 + fr;
#pragma unroll
      for (int r = 0; r < 4; r++) {
        long row = m0 + m * 16 + cr0 + r;
        float v = acc[m][n][r] + bv[n] + bf2f(resid[row * (long)N + col]);
        acc[m][n][r] = v;
        ps[m][r] += v; pq[m][r] += v * v;
      }
    }
  }
  // reduce over the 16 fr lanes (xor offsets stay within the lq group)
#pragma unroll
  for (int off = 1; off < 16; off <<= 1) {
#pragma unroll
    for (int m = 0; m < 4; m++)
#pragma unroll
      for (int r = 0; r < 4; r++) {
        ps[m][r] += __shfl_xor(ps[m][r], off);
        pq[m][r] += __shfl_xor(pq[m][r], off);
      }
  }
  if (fr == 0) {
#pragma unroll
    for (int m = 0; m < 4; m++)
#pragma unroll
      for (int r = 0; r < 4; r++) {
        int rl = m * 16 + cr0 + r;
        rs[rl * 8 + w] = ps[m][r];
        qs[rl * 8 + w] = pq[m][r];
      }
  }
  __syncthreads();
  if (tid < 64) {
    float s = 0.f, q = 0.f;
#pragma unroll
    for (int wv = 0; wv < 8; wv++) { s += rs[tid * 8 + wv]; q += qs[tid * 8 + wv]; }
    float mu = s * (1.f / 512.f);
    float var = q * (1.f / 512.f) - mu * mu;
    mus[tid] = mu; rsds[tid] = rsqrtf(var + 1e-5f);
  }
  __syncthreads();
#pragma unroll
  for (int m = 0; m < 4; m++) {
#pragma unroll
    for (int r = 0; r < 4; r++) {
      int rl = m * 16 + cr0 + r;
      float mu = mus[rl], rstd = rsds[rl];
      long row = m0 + rl;
#pragma unroll
      for (int n = 0; n < 4; n++) {
        int col = w * 64 + n * 16 + fr;
        Out[row * (long)N + col] = (acc[m][n][r] - mu) * rstd * lw[n] + lb[n];
      }
    }
  }
}

// -------- scan pass 2: chunk-carry scan over E (float2, interleaved) --------
__global__ void k_scan_carry(const float2* __restrict__ E2, const float* __restrict__ lam,
                             float2* __restrict__ P2) {
  int idx = blockIdx.x * 256 + threadIdx.x;   // 8192 = B * HIDC
  int b = idx >> 10, d = idx & (HIDC - 1);
  float lr = lam[d], li = lam[HIDC + d];
  float ar = lr, ai = li;                     // lam^128 via 7 squarings
  for (int s = 0; s < 7; s++) { float nr = ar * ar - ai * ai; float ni = 2.f * ar * ai; ar = nr; ai = ni; }
  float pr = 0.f, pi = 0.f;
  for (int c = 0; c < NCH; c++) {
    P2[((long)b * NCH + c) * HIDC + d] = make_float2(pr, pi);
    float2 e = E2[((long)b * NCH + c) * HIDC + d];
    float nr = e.x + ar * pr - ai * pi;
    float ni = e.y + ar * pi + ai * pr;
    pr = nr; pi = ni;
  }
}

// -------- scan pass 3: finalize with carry-in, in place on ubuf (u32 pairs) --------
__global__ void k_scan_final(unsigned int* __restrict__ u,    // ubuf as u32[16384][1024]
                             const float* __restrict__ lam,
                             const float* __restrict__ mask,
                             const float2* __restrict__ P2) {
  int b = blockIdx.x, c = blockIdx.y, dg = blockIdx.z, t = threadIdx.x;
  int d = dg * 256 + t;
  float lr = lam[d], li = lam[HIDC + d];
  float2 pc = P2[((long)b * NCH + c) * HIDC + d];
  float hr = pc.x, hi = pc.y;
  unsigned int* up = u + ((long)(b * L_SZ + c * LCH)) * HIDC + d;
  const float* mrow = mask + b * L_SZ + c * LCH;
  for (int l = 0; l < LCH; l++) {
    unsigned int v = up[(long)l * HIDC];
    float xr = bf2f((unsigned short)(v & 0xffffu));
    float xi = bf2f((unsigned short)(v >> 16));
    float g = (c * LCH + l > 0) ? mrow[l - 1] : 0.f;
    float nr = xr + g * (lr * hr - li * hi);
    float ni = xi + g * (lr * hi + li * hr);
    hr = nr; hi = ni;
    up[(long)l * HIDC] = (unsigned int)f2bf(hr) | ((unsigned int)f2bf(hi) << 16);
  }
}

// ---------------- launch ----------------
extern "C" void kernel_launch(void* const* d_in, const int* in_sizes, int n_in,
                              void* d_out, int out_size, void* d_ws, size_t ws_size,
                              hipStream_t stream) {
  (void)in_sizes; (void)n_in; (void)out_size; (void)ws_size;
  const float* x         = (const float*)d_in[0];
  const float* mask      = (const float*)d_in[1];
  const float* nu_log    = (const float*)d_in[2];
  const float* theta_log = (const float*)d_in[3];
  const float* gamma_log = (const float*)d_in[4];
  const float* W_in_r    = (const float*)d_in[5];
  const float* W_in_i    = (const float*)d_in[6];
  const float* b_in_r    = (const float*)d_in[7];
  const float* b_in_i    = (const float*)d_in[8];
  const float* W_out_r   = (const float*)d_in[9];
  const float* W_out_i   = (const float*)d_in[10];
  const float* b_out_r   = (const float*)d_in[11];
  const float* ln_w      = (const float*)d_in[13];
  const float* ln_b      = (const float*)d_in[14];

  char* ws = (char*)d_ws;
  unsigned short* ubuf = (unsigned short*)(ws);              // 67,108,864
  unsigned short* xb   = (unsigned short*)(ws + 67108864);   // 16,777,216
  unsigned short* W1b  = (unsigned short*)(ws + 83886080);   // 2,097,152
  unsigned short* W2b  = (unsigned short*)(ws + 85983232);   // 2,097,152
  float*  b1   = (float*)(ws + 88080384);                    // 8,192
  float*  lam  = (float*)(ws + 88088576);                    // 8,192
  float2* Ebuf = (float2*)(ws + 88096768);                   // 1,048,576
  float2* Pbuf = (float2*)(ws + 89145344);                   // 1,048,576

  const int LDS1 = 3 * (256 + 128) * 32 * 2;                 // 73728 (gemm1_fused)
  const int LDS2 = 4 * (64 + 512) * 32 * 2;                  // 147456 (gemm2_ln)
  hipFuncSetAttribute((const void*)gemm1_fused,
                      hipFuncAttributeMaxDynamicSharedMemorySize, LDS1);
  hipFuncSetAttribute((const void*)gemm2_ln,
                      hipFuncAttributeMaxDynamicSharedMemorySize, LDS2);

  k_cvt_x   <<<8192, 256, 0, stream>>>(x, xb);
  k_prep_all<<<8196, 256, 0, stream>>>(W_in_r, W_in_i, b_in_r, b_in_i, gamma_log,
                                       W_out_r, W_out_i, nu_log, theta_log,
                                       W1b, b1, W2b, lam);

  // GEMM1 + fused scan pass 1: 1024 WGs
  gemm1_fused<<<1024, 256, LDS1, stream>>>(xb, W1b, ubuf, b1, lam, mask, Ebuf);

  // scan passes 2, 3
  k_scan_carry<<<32, 256, 0, stream>>>(Ebuf, lam, Pbuf);
  k_scan_final<<<dim3(B_SZ, NCH, HIDC / 256), 256, 0, stream>>>(
      (unsigned int*)ubuf, lam, mask, Pbuf);

  // GEMM2 + fused LayerNorm: 256 WGs (full-row blocks)
  gemm2_ln<<<256, 512, LDS2, stream>>>(ubuf, W2b, (float*)d_out, b_out_r, xb,
                                       ln_w, ln_b);
}